// Round 2
// baseline (340.963 us; speedup 1.0000x reference)
//
#include <hip/hip_runtime.h>

typedef __attribute__((ext_vector_type(8))) __bf16 bf16x8;
typedef __attribute__((ext_vector_type(4))) float f32x4;
typedef __attribute__((ext_vector_type(4))) float floatx4;
typedef __attribute__((ext_vector_type(8))) unsigned short ushortx8;

__device__ inline unsigned short f2bf(float f) {
  unsigned int u = __float_as_uint(f);
  unsigned int r = (u + 0x7FFFu + ((u >> 16) & 1u)) >> 16;  // RNE
  return (unsigned short)r;
}

// ---------------- P0: convert x (N x 128 f32) -> bf16 ----------------
__global__ __launch_bounds__(256) void conv_kernel(const float* __restrict__ x,
                                                   unsigned short* __restrict__ xb,
                                                   int total8) {
  int id = blockIdx.x * 256 + threadIdx.x;
  if (id >= total8) return;
  floatx4 f0 = ((const floatx4*)x)[2 * id];
  floatx4 f1 = ((const floatx4*)x)[2 * id + 1];
  ushortx8 r;
  r[0] = f2bf(f0[0]); r[1] = f2bf(f0[1]); r[2] = f2bf(f0[2]); r[3] = f2bf(f0[3]);
  r[4] = f2bf(f1[0]); r[5] = f2bf(f1[1]); r[6] = f2bf(f1[2]); r[7] = f2bf(f1[3]);
  ((ushortx8*)xb)[id] = r;
}

// ---------------- P1: build W_r^T (bf16), wbt[r][o][d], r in [0,33) ----------------
__global__ __launch_bounds__(256) void wbuild_kernel(const float* __restrict__ bases,
                                                     const float* __restrict__ rbw,
                                                     unsigned short* __restrict__ wbt) {
  int id = blockIdx.x * 256 + threadIdx.x;
  if (id >= 33 * 16384) return;
  int r = id >> 14, rem = id & 16383, o = rem >> 7, d = rem & 127;
  float acc = 0.f;
#pragma unroll
  for (int b = 0; b < 8; ++b) acc += rbw[r * 8 + b] * bases[b * 16384 + d * 128 + o];
  wbt[id] = f2bf(acc);
}

// ---------------- D: sniff mask dtype. flag: 0=int32, 1=byte/bool, 2=float32 ----------------
__global__ void detect_kernel(const unsigned char* __restrict__ mask, int nbytes,
                              int* __restrict__ flag_out) {
  __shared__ int nz_off, big;
  if (threadIdx.x == 0) { nz_off = 0; big = 0; }
  __syncthreads();
  int lnz = 0, lbig = 0;
  for (int i = threadIdx.x; i < nbytes; i += 256) {
    unsigned char v = mask[i];
    if ((i & 3) && v) lnz++;
    if (v > 1) lbig++;
  }
  if (lnz) atomicAdd(&nz_off, lnz);
  if (lbig) atomicAdd(&big, lbig);
  __syncthreads();
  if (threadIdx.x == 0) {
    int f = (nz_off == 0) ? 0 : ((big == 0) ? 1 : 2);
    *flag_out = f;
  }
}

// meta layout (ints): cnt[r] at [r*16]; cursor[r] at [512+r*16];
// off[r] at [1024+r] (33); bs[r] at [1088+r] (33); mask dtype flag at [2046]
// ---------------- S1: histogram of edge_type ----------------
__global__ __launch_bounds__(256) void hist_kernel(const int* __restrict__ et, int E,
                                                   int* __restrict__ meta) {
  __shared__ int h[32];
  if (threadIdx.x < 32) h[threadIdx.x] = 0;
  __syncthreads();
  for (int i = blockIdx.x * blockDim.x + threadIdx.x; i < E; i += gridDim.x * blockDim.x)
    atomicAdd(&h[et[i]], 1);
  __syncthreads();
  if (threadIdx.x < 32 && h[threadIdx.x] > 0) atomicAdd(&meta[threadIdx.x * 16], h[threadIdx.x]);
}

// ---------------- S2: exclusive scan (tiny, 1 thread) ----------------
__global__ void scan_kernel(int* __restrict__ meta) {
  if (threadIdx.x == 0 && blockIdx.x == 0) {
    int acc = 0, bacc = 0;
    for (int r = 0; r < 32; ++r) {
      int c = meta[r * 16];
      meta[1024 + r] = acc;
      meta[512 + r * 16] = acc;
      meta[1088 + r] = bacc;
      acc += c;
      bacc += (c + 31) >> 5;
    }
    meta[1024 + 32] = acc;
    meta[1088 + 32] = bacc;
  }
}

// ---------------- S3: block-aggregated scatter into perm ----------------
#define SC_CHUNK 2048
__global__ __launch_bounds__(256) void scatter_kernel(const int* __restrict__ et, int E,
                                                      int* __restrict__ meta,
                                                      int* __restrict__ perm) {
  __shared__ int lcnt[32], lbase[32], lpos[32];
  int t = threadIdx.x;
  if (t < 32) { lcnt[t] = 0; lpos[t] = 0; }
  __syncthreads();
  int start = blockIdx.x * SC_CHUNK;
  int end = min(start + SC_CHUNK, E);
  for (int i = start + t; i < end; i += blockDim.x) atomicAdd(&lcnt[et[i]], 1);
  __syncthreads();
  if (t < 32 && lcnt[t] > 0) lbase[t] = atomicAdd(&meta[512 + t * 16], lcnt[t]);
  __syncthreads();
  for (int i = start + t; i < end; i += blockDim.x) {
    int r = et[i];
    int p = atomicAdd(&lpos[r], 1);
    perm[lbase[r] + p] = i;
  }
}

// ---------------- K_self: out[n] = mask[n] ? x[n] @ W_self : 0 ----------------
__global__ __launch_bounds__(256) void self_kernel(const unsigned short* __restrict__ xb,
                                                   const unsigned short* __restrict__ wbt,
                                                   const void* __restrict__ maskp,
                                                   const int* __restrict__ meta,
                                                   float* __restrict__ out, int N) {
  int flag = meta[2046];
  int nb = blockIdx.x * 64;
  int lane = threadIdx.x & 63, wid = threadIdx.x >> 6;
  int Rb = (wid >> 1) * 32, Cb = (wid & 1) * 64;
  int l15 = lane & 15, lk = (lane >> 4) * 8;
  const unsigned short* wself = wbt + 32 * 16384;
  f32x4 acc[2][4] = {};
  int an[2];
#pragma unroll
  for (int mt = 0; mt < 2; ++mt) {
    int n = nb + Rb + 16 * mt + l15;
    an[mt] = (n < N) ? n : 0;
  }
#pragma unroll
  for (int kb = 0; kb < 4; ++kb) {
    int k0 = kb * 32 + lk;
    bf16x8 a[2], b[4];
#pragma unroll
    for (int mt = 0; mt < 2; ++mt) a[mt] = *(const bf16x8*)(xb + (size_t)an[mt] * 128 + k0);
#pragma unroll
    for (int nt = 0; nt < 4; ++nt) {
      int col = Cb + 16 * nt + l15;
      b[nt] = *(const bf16x8*)(wself + col * 128 + k0);
    }
#pragma unroll
    for (int mt = 0; mt < 2; ++mt)
#pragma unroll
      for (int nt = 0; nt < 4; ++nt)
        acc[mt][nt] = __builtin_amdgcn_mfma_f32_16x16x32_bf16(a[mt], b[nt], acc[mt][nt], 0, 0, 0);
  }
#pragma unroll
  for (int mt = 0; mt < 2; ++mt) {
    int rowb = nb + Rb + 16 * mt + (lane >> 4) * 4;
#pragma unroll
    for (int i = 0; i < 4; ++i) {
      int n = rowb + i;
      if (n < N) {
        bool keep;
        if (flag == 0)      keep = ((const int*)maskp)[n] != 0;
        else if (flag == 1) keep = ((const unsigned char*)maskp)[n] != 0;
        else                keep = ((const float*)maskp)[n] != 0.f;
        float m = keep ? 1.f : 0.f;
#pragma unroll
        for (int nt = 0; nt < 4; ++nt) {
          int col = Cb + 16 * nt + l15;
          out[(size_t)n * 128 + col] = acc[mt][nt][i] * m;
        }
      }
    }
  }
}

// ---------------- K_edge: per-relation groups of 32 edges (64 message rows) ----------------
__global__ __launch_bounds__(256) void edge_kernel(const unsigned short* __restrict__ xb,
                                                   const unsigned short* __restrict__ wbt,
                                                   const int* __restrict__ src,
                                                   const int* __restrict__ tgt,
                                                   const float* __restrict__ ew,
                                                   const int* __restrict__ perm,
                                                   const int* __restrict__ meta,
                                                   float* __restrict__ out) {
  __shared__ int sbs[33];
  __shared__ int rowsrc[64];
  __shared__ int rowtgt[64];
  __shared__ float roww[64];
  int t = threadIdx.x;
  if (t < 33) sbs[t] = meta[1088 + t];
  __syncthreads();
  int b = blockIdx.x;
  if (b >= sbs[32]) return;
  int r = 0;
  while (sbs[r + 1] <= b) ++r;  // uniform, <=32 iters
  int off_r = meta[1024 + r];
  int cnt_r = meta[1024 + r + 1] - off_r;
  int chunk = b - sbs[r];
  int e0 = off_r + chunk * 32;
  int ecnt = min(32, off_r + cnt_r - e0);
  if (t < 32) {
    if (t < ecnt) {
      int e = perm[e0 + t];
      int s = src[e], g = tgt[e];
      float w = ew[e];
      rowsrc[2 * t] = s;     rowtgt[2 * t] = g;     roww[2 * t] = w;
      rowsrc[2 * t + 1] = g; rowtgt[2 * t + 1] = s; roww[2 * t + 1] = w;
    } else {
      rowsrc[2 * t] = 0;     rowtgt[2 * t] = 0;     roww[2 * t] = 0.f;
      rowsrc[2 * t + 1] = 0; rowtgt[2 * t + 1] = 0; roww[2 * t + 1] = 0.f;
    }
  }
  __syncthreads();
  int lane = t & 63, wid = t >> 6;
  int Rb = (wid >> 1) * 32, Cb = (wid & 1) * 64;
  int l15 = lane & 15, lk = (lane >> 4) * 8;
  const unsigned short* w_r = wbt + (size_t)r * 16384;
  f32x4 acc[2][4] = {};
  int an[2];
#pragma unroll
  for (int mt = 0; mt < 2; ++mt) an[mt] = rowsrc[Rb + 16 * mt + l15];
#pragma unroll
  for (int kb = 0; kb < 4; ++kb) {
    int k0 = kb * 32 + lk;
    bf16x8 a[2], bf[4];
#pragma unroll
    for (int mt = 0; mt < 2; ++mt) a[mt] = *(const bf16x8*)(xb + (size_t)an[mt] * 128 + k0);
#pragma unroll
    for (int nt = 0; nt < 4; ++nt) {
      int col = Cb + 16 * nt + l15;
      bf[nt] = *(const bf16x8*)(w_r + col * 128 + k0);
    }
#pragma unroll
    for (int mt = 0; mt < 2; ++mt)
#pragma unroll
      for (int nt = 0; nt < 4; ++nt)
        acc[mt][nt] = __builtin_amdgcn_mfma_f32_16x16x32_bf16(a[mt], bf[nt], acc[mt][nt], 0, 0, 0);
  }
#pragma unroll
  for (int mt = 0; mt < 2; ++mt) {
    int rowb = Rb + 16 * mt + (lane >> 4) * 4;
#pragma unroll
    for (int i = 0; i < 4; ++i) {
      int row = rowb + i;
      float w = roww[row];
      if (w != 0.f) {
        int g = rowtgt[row];
#pragma unroll
        for (int nt = 0; nt < 4; ++nt) {
          int col = Cb + 16 * nt + l15;
          atomicAdd(&out[(size_t)g * 128 + col], acc[mt][nt][i] * w);
        }
      }
    }
  }
}

extern "C" void kernel_launch(void* const* d_in, const int* in_sizes, int n_in,
                              void* d_out, int out_size, void* d_ws, size_t ws_size,
                              hipStream_t stream) {
  const float* x = (const float*)d_in[0];
  const void* mask = d_in[1];
  const int* source = (const int*)d_in[2];
  const int* target = (const int*)d_in[3];
  const int* etype = (const int*)d_in[4];
  const float* eweight = (const float*)d_in[5];
  const float* bases = (const float*)d_in[6];
  const float* rbw = (const float*)d_in[7];
  float* out = (float*)d_out;

  const int N = in_sizes[0] / 128;
  const int E = in_sizes[2];

  // workspace layout
  char* ws = (char*)d_ws;
  unsigned short* wbt = (unsigned short*)ws;                      // 33*16384*2 = 1,081,344 B
  unsigned short* xb = (unsigned short*)(ws + 1081344);           // N*128*2 B
  int* meta = (int*)(ws + 1081344 + (size_t)N * 256);             // 2048 ints
  int* perm = meta + 2048;                                        // E ints

  hipMemsetAsync(meta, 0, 2048 * sizeof(int), stream);

  int total8 = (N * 128) / 8;
  detect_kernel<<<1, 256, 0, stream>>>((const unsigned char*)mask, min(N, 8192), &meta[2046]);
  conv_kernel<<<(total8 + 255) / 256, 256, 0, stream>>>(x, xb, total8);
  wbuild_kernel<<<(33 * 16384 + 255) / 256, 256, 0, stream>>>(bases, rbw, wbt);
  hist_kernel<<<128, 256, 0, stream>>>(etype, E, meta);
  scan_kernel<<<1, 64, 0, stream>>>(meta);
  scatter_kernel<<<(E + SC_CHUNK - 1) / SC_CHUNK, 256, 0, stream>>>(etype, E, meta, perm);
  self_kernel<<<(N + 63) / 64, 256, 0, stream>>>(xb, wbt, mask, meta, out, N);
  int nblk = (E + 31) / 32 + 32;  // upper bound; blocks beyond bs[32] early-exit
  edge_kernel<<<nblk, 256, 0, stream>>>(xb, wbt, source, target, eweight, perm, meta, out);
}

// Round 4
// 314.215 us; speedup vs baseline: 1.0851x; 1.0851x over previous
//
#include <hip/hip_runtime.h>

typedef __attribute__((ext_vector_type(8))) __bf16 bf16x8;
typedef __attribute__((ext_vector_type(4))) float f32x4;
typedef __attribute__((ext_vector_type(8))) unsigned short ushortx8;

__device__ inline unsigned short f2bf(float f) {
  unsigned int u = __float_as_uint(f);
  unsigned int r = (u + 0x7FFFu + ((u >> 16) & 1u)) >> 16;  // RNE
  return (unsigned short)r;
}

// ---------------- P0: convert x (N x 128 f32) -> bf16 ----------------
__global__ __launch_bounds__(256) void conv_kernel(const float* __restrict__ x,
                                                   unsigned short* __restrict__ xb,
                                                   int total8) {
  int id = blockIdx.x * 256 + threadIdx.x;
  if (id >= total8) return;
  f32x4 f0 = ((const f32x4*)x)[2 * id];
  f32x4 f1 = ((const f32x4*)x)[2 * id + 1];
  ushortx8 r;
  r[0] = f2bf(f0[0]); r[1] = f2bf(f0[1]); r[2] = f2bf(f0[2]); r[3] = f2bf(f0[3]);
  r[4] = f2bf(f1[0]); r[5] = f2bf(f1[1]); r[6] = f2bf(f1[2]); r[7] = f2bf(f1[3]);
  ((ushortx8*)xb)[id] = r;
}

// ---------------- P1: BmatT[o][k] = bases[b][d][o], k=b*128+d, bf16 ----------------
__global__ __launch_bounds__(256) void tconv_kernel(const float* __restrict__ bases,
                                                    unsigned short* __restrict__ bmt) {
  int id = blockIdx.x * 256 + threadIdx.x;
  if (id >= 128 * 1024) return;
  int o = id >> 10, k = id & 1023, b = k >> 7, d = k & 127;
  bmt[id] = f2bf(bases[b * 16384 + d * 128 + o]);
}

// ---------------- D: sniff mask dtype. 0=int32, 1=byte/bool, 2=float32 ----------------
__global__ void detect_kernel(const unsigned char* __restrict__ mask, int nbytes,
                              int* __restrict__ flag_out) {
  __shared__ int nz_off, big;
  if (threadIdx.x == 0) { nz_off = 0; big = 0; }
  __syncthreads();
  int lnz = 0, lbig = 0;
  for (int i = threadIdx.x; i < nbytes; i += 256) {
    unsigned char v = mask[i];
    if ((i & 3) && v) lnz++;
    if (v > 1) lbig++;
  }
  if (lnz) atomicAdd(&nz_off, lnz);
  if (lbig) atomicAdd(&big, lbig);
  __syncthreads();
  if (threadIdx.x == 0) *flag_out = (nz_off == 0) ? 0 : ((big == 0) ? 1 : 2);
}

// ---------------- S1: histogram over target nodes (both directions) ----------------
__global__ __launch_bounds__(256) void hist_kernel(const int* __restrict__ src,
                                                   const int* __restrict__ tgt, int E,
                                                   int* __restrict__ cnt) {
  int i = blockIdx.x * 256 + threadIdx.x;
  if (i >= E) return;
  atomicAdd(&cnt[tgt[i]], 1);
  atomicAdd(&cnt[src[i]], 1);
}

// ---------------- S2a: per-block sums ----------------
__global__ __launch_bounds__(256) void scan1_kernel(const int* __restrict__ cnt, int N,
                                                    int* __restrict__ bsum) {
  __shared__ int s[256];
  int t = threadIdx.x, i = blockIdx.x * 256 + t;
  s[t] = (i < N) ? cnt[i] : 0;
  __syncthreads();
#pragma unroll
  for (int off = 128; off > 0; off >>= 1) {
    if (t < off) s[t] += s[t + off];
    __syncthreads();
  }
  if (t == 0) bsum[blockIdx.x] = s[0];
}

// ---------------- S2b: scan block sums (nb <= 512) ----------------
__global__ void scan2_kernel(const int* __restrict__ bsum, int nb,
                             int* __restrict__ bexcl, int* __restrict__ base, int N) {
  __shared__ int s[512];
  int t = threadIdx.x;
  int v = (t < nb) ? bsum[t] : 0;
  s[t] = v;
  __syncthreads();
  for (int off = 1; off < 512; off <<= 1) {
    int x = (t >= off) ? s[t - off] : 0;
    __syncthreads();
    s[t] += x;
    __syncthreads();
  }
  if (t < nb) bexcl[t] = s[t] - v;
  if (t == nb - 1) base[N] = s[t];
}

// ---------------- S2c: per-element exclusive base + cursor ----------------
__global__ __launch_bounds__(256) void scan3_kernel(const int* __restrict__ cnt, int N,
                                                    const int* __restrict__ bexcl,
                                                    int* __restrict__ base,
                                                    int* __restrict__ cursor) {
  __shared__ int s[256];
  int t = threadIdx.x, i = blockIdx.x * 256 + t;
  int c = (i < N) ? cnt[i] : 0;
  s[t] = c;
  __syncthreads();
  for (int off = 1; off < 256; off <<= 1) {
    int x = (t >= off) ? s[t - off] : 0;
    __syncthreads();
    s[t] += x;
    __syncthreads();
  }
  if (i < N) {
    int v = bexcl[blockIdx.x] + s[t] - c;
    base[i] = v;
    cursor[i] = v;
  }
}

// ---------------- S3: scatter messages into target-sorted arrays ----------------
__global__ __launch_bounds__(256) void scatter_kernel(const int* __restrict__ src,
                                                      const int* __restrict__ tgt,
                                                      const int* __restrict__ et,
                                                      const float* __restrict__ ew, int E,
                                                      int* __restrict__ cursor,
                                                      unsigned* __restrict__ msr,
                                                      float* __restrict__ mwt) {
  int i = blockIdx.x * 256 + threadIdx.x;
  if (i >= E) return;
  int s = src[i], g = tgt[i], r = et[i];
  float w = ew[i];
  int s1 = atomicAdd(&cursor[g], 1);
  msr[s1] = (unsigned)s | ((unsigned)r << 24);
  mwt[s1] = w;
  int s2 = atomicAdd(&cursor[s], 1);
  msr[s2] = (unsigned)g | ((unsigned)r << 24);
  mwt[s2] = w;
}

// ---------------- K: per-target gather (z accumulate) + block MFMA projection ----------------
// block = 256 thr (4 waves), owns 32 target rows; wave w owns targets [w*8, w*8+8)
// LDS: zs = 32 rows x 1024 k of bf16 (XOR-swizzled), 65536 B; ctab = 264 floats
__global__ __launch_bounds__(256, 2) void gather_kernel(
    const unsigned* __restrict__ xb32, const unsigned short* __restrict__ bmt,
    const int* __restrict__ base, const unsigned* __restrict__ msr,
    const float* __restrict__ mwt, const float* __restrict__ rbw,
    const void* __restrict__ maskp, const int* __restrict__ flag_p,
    float* __restrict__ out, int N) {
  extern __shared__ char smem[];
  float* ctab = (float*)(smem + 65536);                // 264 floats
  int t = threadIdx.x;
  for (int i = t; i < 264; i += 256) ctab[i] = rbw[i];   // FIX: cover 256..263
  int wid = t >> 6, l = t & 63;
  int t0 = blockIdx.x * 32;
  int flag = *flag_p;
  __syncthreads();

  for (int j = 0; j < 8; ++j) {
    int tg = t0 + wid * 8 + j;
    int tgc = (tg < N) ? tg : (N - 1);
    // self-loop seed
    unsigned xs = xb32[(size_t)tgc * 64 + l];
    bool keep;
    if (flag == 0)      keep = ((const int*)maskp)[tgc] != 0;
    else if (flag == 1) keep = ((const unsigned char*)maskp)[tgc] != 0;
    else                keep = ((const float*)maskp)[tgc] != 0.f;
    float ms = (keep && tg < N) ? 1.f : 0.f;
    float slo = __uint_as_float(xs << 16);
    float shi = __uint_as_float(xs & 0xFFFF0000u);
    float zlo[8], zhi[8];
#pragma unroll
    for (int b = 0; b < 8; ++b) {
      float a = ms * ctab[256 + b];
      zlo[b] = a * slo;
      zhi[b] = a * shi;
    }
    // message loop (2-deep pipelined)
    int beg = base[tgc];
    int cnt = (tg < N) ? (base[tgc + 1] - beg) : 0;
    unsigned sr0 = 0, sr1 = 0, x0 = 0;
    float w0 = 0.f, w1 = 0.f;
    if (cnt > 0) { sr0 = msr[beg]; w0 = mwt[beg]; }
    if (cnt > 1) { sr1 = msr[beg + 1]; w1 = mwt[beg + 1]; }
    if (cnt > 0) x0 = xb32[(size_t)(sr0 & 0xFFFFFu) * 64 + l];
    for (int m = 0; m < cnt; ++m) {
      int i2 = (m + 2 < cnt) ? (beg + m + 2) : beg;
      unsigned sr2 = msr[i2];
      float w2 = (m + 2 < cnt) ? mwt[i2] : 0.f;
      unsigned x1 = xb32[(size_t)(sr1 & 0xFFFFFu) * 64 + l];
      int rel = sr0 >> 24;
      f32x4 c0 = *(const f32x4*)&ctab[rel * 8];
      f32x4 c1 = *(const f32x4*)&ctab[rel * 8 + 4];
      float cc[8] = {c0[0], c0[1], c0[2], c0[3], c1[0], c1[1], c1[2], c1[3]};
      float lo = __uint_as_float(x0 << 16);
      float hi = __uint_as_float(x0 & 0xFFFF0000u);
#pragma unroll
      for (int b = 0; b < 8; ++b) {
        float a = w0 * cc[b];
        zlo[b] = fmaf(a, lo, zlo[b]);
        zhi[b] = fmaf(a, hi, zhi[b]);
      }
      sr0 = sr1; w0 = w1; x0 = x1;
      sr1 = sr2; w1 = w2;
    }
    // flush z row to LDS (bf16, XOR swizzle on bits 4-6)
    int row = wid * 8 + j;
#pragma unroll
    for (int b = 0; b < 8; ++b) {
      unsigned pk = (unsigned)f2bf(zlo[b]) | ((unsigned)f2bf(zhi[b]) << 16);
      int byte = row * 2048 + ((b * 256 + l * 4) ^ ((row & 7) << 4));
      *(unsigned*)(smem + byte) = pk;
    }
  }
  __syncthreads();

  // MFMA: out[32 x 128] = Z(32 x 1024, bf16) @ Bstack(1024 x 128); wave owns 32 cols
  int l15 = l & 15, lk8 = (l >> 4) * 8;
  f32x4 acc[2][2] = {};
  for (int ks = 0; ks < 32; ++ks) {
    int k0 = ks * 32 + lk8;
    bf16x8 a[2], bb[2];
#pragma unroll
    for (int rt = 0; rt < 2; ++rt) {
      int tr = rt * 16 + l15;
      int byte = tr * 2048 + ((k0 * 2) ^ ((tr & 7) << 4));
      a[rt] = *(const bf16x8*)(smem + byte);
    }
#pragma unroll
    for (int ct = 0; ct < 2; ++ct) {
      int col = wid * 32 + ct * 16 + l15;
      bb[ct] = *(const bf16x8*)(bmt + (size_t)col * 1024 + k0);
    }
#pragma unroll
    for (int rt = 0; rt < 2; ++rt)
#pragma unroll
      for (int ct = 0; ct < 2; ++ct)
        acc[rt][ct] = __builtin_amdgcn_mfma_f32_16x16x32_bf16(a[rt], bb[ct], acc[rt][ct], 0, 0, 0);
  }
#pragma unroll
  for (int rt = 0; rt < 2; ++rt) {
    int rowb = t0 + rt * 16 + (l >> 4) * 4;
#pragma unroll
    for (int i = 0; i < 4; ++i) {
      int row = rowb + i;
      if (row < N) {
#pragma unroll
        for (int ct = 0; ct < 2; ++ct) {
          int col = wid * 32 + ct * 16 + l15;
          out[(size_t)row * 128 + col] = acc[rt][ct][i];
        }
      }
    }
  }
}

extern "C" void kernel_launch(void* const* d_in, const int* in_sizes, int n_in,
                              void* d_out, int out_size, void* d_ws, size_t ws_size,
                              hipStream_t stream) {
  const float* x = (const float*)d_in[0];
  const void* mask = d_in[1];
  const int* source = (const int*)d_in[2];
  const int* target = (const int*)d_in[3];
  const int* etype = (const int*)d_in[4];
  const float* eweight = (const float*)d_in[5];
  const float* bases = (const float*)d_in[6];
  const float* rbw = (const float*)d_in[7];
  float* out = (float*)d_out;

  const int N = in_sizes[1];   // mask element count == num nodes
  const int E = in_sizes[2];
  const int M = 2 * E;
  const int NB = (N + 255) / 256;

  // workspace layout (256B aligned)
  char* ws = (char*)d_ws;
  size_t off = 0;
  unsigned short* xb = (unsigned short*)(ws + off); off += (size_t)N * 256;        // bf16 x
  unsigned short* bmt = (unsigned short*)(ws + off); off += 128 * 1024 * 2;        // BmatT
  unsigned* msr = (unsigned*)(ws + off); off += (size_t)M * 4;                     // src|rel
  float* mwt = (float*)(ws + off); off += (size_t)M * 4;                           // weights
  int* base = (int*)(ws + off); off += ((size_t)N + 64) * 4;                       // N+1 scan
  int* cursor = (int*)(ws + off); off += ((size_t)N + 64) * 4;
  int* cnt = (int*)(ws + off); off += ((size_t)N + 64) * 4;
  int* bsum = (int*)(ws + off); off += 2048;
  int* bexcl = (int*)(ws + off); off += 2048;
  int* flag = (int*)(ws + off); off += 256;

  hipMemsetAsync(cnt, 0, (size_t)N * 4, stream);
  detect_kernel<<<1, 256, 0, stream>>>((const unsigned char*)mask, N < 8192 ? N : 8192, flag);
  int total8 = (N * 128) / 8;
  conv_kernel<<<(total8 + 255) / 256, 256, 0, stream>>>(x, xb, total8);
  tconv_kernel<<<(128 * 1024 + 255) / 256, 256, 0, stream>>>(bases, bmt);
  hist_kernel<<<(E + 255) / 256, 256, 0, stream>>>(source, target, E, cnt);
  scan1_kernel<<<NB, 256, 0, stream>>>(cnt, N, bsum);
  scan2_kernel<<<1, 512, 0, stream>>>(bsum, NB, bexcl, base, N);
  scan3_kernel<<<NB, 256, 0, stream>>>(cnt, N, bexcl, base, cursor);
  scatter_kernel<<<(E + 255) / 256, 256, 0, stream>>>(source, target, etype, eweight, E,
                                                      cursor, msr, mwt);
  int gblk = (N + 31) / 32;
  size_t shmem = 65536 + 264 * sizeof(float) + 16;
  gather_kernel<<<gblk, 256, shmem, stream>>>((const unsigned*)xb, bmt, base, msr, mwt,
                                              rbw, mask, flag, out, N);
}

// Round 5
// 282.952 us; speedup vs baseline: 1.2050x; 1.1105x over previous
//
#include <hip/hip_runtime.h>

typedef __attribute__((ext_vector_type(8))) __bf16 bf16x8;
typedef __attribute__((ext_vector_type(4))) float f32x4;
typedef __attribute__((ext_vector_type(8))) unsigned short ushortx8;

__device__ inline unsigned short f2bf(float f) {
  unsigned int u = __float_as_uint(f);
  unsigned int r = (u + 0x7FFFu + ((u >> 16) & 1u)) >> 16;  // RNE
  return (unsigned short)r;
}

// ---------------- P0: convert x (N x 128 f32) -> bf16 ----------------
__global__ __launch_bounds__(256) void conv_kernel(const float* __restrict__ x,
                                                   unsigned short* __restrict__ xb,
                                                   int total8) {
  int id = blockIdx.x * 256 + threadIdx.x;
  if (id >= total8) return;
  f32x4 f0 = ((const f32x4*)x)[2 * id];
  f32x4 f1 = ((const f32x4*)x)[2 * id + 1];
  ushortx8 r;
  r[0] = f2bf(f0[0]); r[1] = f2bf(f0[1]); r[2] = f2bf(f0[2]); r[3] = f2bf(f0[3]);
  r[4] = f2bf(f1[0]); r[5] = f2bf(f1[1]); r[6] = f2bf(f1[2]); r[7] = f2bf(f1[3]);
  ((ushortx8*)xb)[id] = r;
}

// ---------------- P1: BmatT[o][k] = bases[b][d][o], k=b*128+d, bf16 ----------------
__global__ __launch_bounds__(256) void tconv_kernel(const float* __restrict__ bases,
                                                    unsigned short* __restrict__ bmt) {
  int id = blockIdx.x * 256 + threadIdx.x;
  if (id >= 128 * 1024) return;
  int o = id >> 10, k = id & 1023, b = k >> 7, d = k & 127;
  bmt[id] = f2bf(bases[b * 16384 + d * 128 + o]);
}

// ---------------- D: sniff mask dtype. 0=int32, 1=byte/bool, 2=float32 ----------------
__global__ void detect_kernel(const unsigned char* __restrict__ mask, int nbytes,
                              int* __restrict__ flag_out) {
  __shared__ int nz_off, big;
  if (threadIdx.x == 0) { nz_off = 0; big = 0; }
  __syncthreads();
  int lnz = 0, lbig = 0;
  for (int i = threadIdx.x; i < nbytes; i += 256) {
    unsigned char v = mask[i];
    if ((i & 3) && v) lnz++;
    if (v > 1) lbig++;
  }
  if (lnz) atomicAdd(&nz_off, lnz);
  if (lbig) atomicAdd(&big, lbig);
  __syncthreads();
  if (threadIdx.x == 0) *flag_out = (nz_off == 0) ? 0 : ((big == 0) ? 1 : 2);
}

// ---------------- S1: histogram over target nodes (both directions) ----------------
__global__ __launch_bounds__(256) void hist_kernel(const int* __restrict__ src,
                                                   const int* __restrict__ tgt, int E,
                                                   int* __restrict__ cnt) {
  int i = blockIdx.x * 256 + threadIdx.x;
  if (i >= E) return;
  atomicAdd(&cnt[tgt[i]], 1);
  atomicAdd(&cnt[src[i]], 1);
}

// ---------------- S2a: per-block sums ----------------
__global__ __launch_bounds__(256) void scan1_kernel(const int* __restrict__ cnt, int N,
                                                    int* __restrict__ bsum) {
  __shared__ int s[256];
  int t = threadIdx.x, i = blockIdx.x * 256 + t;
  s[t] = (i < N) ? cnt[i] : 0;
  __syncthreads();
#pragma unroll
  for (int off = 128; off > 0; off >>= 1) {
    if (t < off) s[t] += s[t + off];
    __syncthreads();
  }
  if (t == 0) bsum[blockIdx.x] = s[0];
}

// ---------------- S2b: scan block sums (nb <= 512) ----------------
__global__ void scan2_kernel(const int* __restrict__ bsum, int nb,
                             int* __restrict__ bexcl, int* __restrict__ base, int N) {
  __shared__ int s[512];
  int t = threadIdx.x;
  int v = (t < nb) ? bsum[t] : 0;
  s[t] = v;
  __syncthreads();
  for (int off = 1; off < 512; off <<= 1) {
    int x = (t >= off) ? s[t - off] : 0;
    __syncthreads();
    s[t] += x;
    __syncthreads();
  }
  if (t < nb) bexcl[t] = s[t] - v;
  if (t == nb - 1) base[N] = s[t];
}

// ---------------- S2c: per-element exclusive base + cursor ----------------
__global__ __launch_bounds__(256) void scan3_kernel(const int* __restrict__ cnt, int N,
                                                    const int* __restrict__ bexcl,
                                                    int* __restrict__ base,
                                                    int* __restrict__ cursor) {
  __shared__ int s[256];
  int t = threadIdx.x, i = blockIdx.x * 256 + t;
  int c = (i < N) ? cnt[i] : 0;
  s[t] = c;
  __syncthreads();
  for (int off = 1; off < 256; off <<= 1) {
    int x = (t >= off) ? s[t - off] : 0;
    __syncthreads();
    s[t] += x;
    __syncthreads();
  }
  if (i < N) {
    int v = bexcl[blockIdx.x] + s[t] - c;
    base[i] = v;
    cursor[i] = v;
  }
}

// ---------------- S3: scatter messages (src|rel, w) into target-sorted array ----------------
__global__ __launch_bounds__(256) void scatter_kernel(const int* __restrict__ src,
                                                      const int* __restrict__ tgt,
                                                      const int* __restrict__ et,
                                                      const float* __restrict__ ew, int E,
                                                      int* __restrict__ cursor,
                                                      uint2* __restrict__ msrw) {
  int i = blockIdx.x * 256 + threadIdx.x;
  if (i >= E) return;
  int s = src[i], g = tgt[i], r = et[i];
  unsigned wbits = __float_as_uint(ew[i]);
  int s1 = atomicAdd(&cursor[g], 1);
  msrw[s1] = make_uint2((unsigned)s | ((unsigned)r << 24), wbits);
  int s2 = atomicAdd(&cursor[s], 1);
  msrw[s2] = make_uint2((unsigned)g | ((unsigned)r << 24), wbits);
}

// ---------------- K: per-target gather (paired) + block MFMA projection ----------------
// block = 512 thr (8 waves), owns 32 target rows; wave w owns targets [w*4, w*4+4) as 2 pairs
// LDS: zs = 32 rows x 1024 k bf16 (XOR-swizzled), 65536 B; ctab = 264 floats
__global__ __launch_bounds__(512, 4) void gather_kernel(
    const unsigned* __restrict__ xb32, const unsigned short* __restrict__ bmt,
    const int* __restrict__ base, const uint2* __restrict__ msrw,
    const float* __restrict__ rbw, const void* __restrict__ maskp,
    const int* __restrict__ flag_p, float* __restrict__ out, int N) {
  extern __shared__ char smem[];
  float* ctab = (float*)(smem + 65536);                // 264 floats
  int t = threadIdx.x;
  for (int i = t; i < 264; i += 512) ctab[i] = rbw[i];
  int wid = t >> 6, l = t & 63;
  int t0 = blockIdx.x * 32;
  int flag = *flag_p;
  __syncthreads();

#pragma unroll
  for (int pr = 0; pr < 2; ++pr) {
    // pair of consecutive targets: A = t0 + wid*4 + pr*2, B = A+1
    int tgA = t0 + wid * 4 + pr * 2;
    int tgc[2], beg[2], cnt[2];
    float zlo[2][8], zhi[2][8];
    uint2 srw0[2], srw1[2];
    unsigned x0[2];
#pragma unroll
    for (int p = 0; p < 2; ++p) {
      int tg = tgA + p;
      tgc[p] = (tg < N) ? tg : (N - 1);
    }
    // base: 3 consecutive loads
    int b0 = base[tgc[0]], b1 = base[tgc[0] + 1], b2 = base[tgc[1] + 1];
    beg[0] = b0; cnt[0] = (tgA < N) ? (b1 - b0) : 0;
    beg[1] = base[tgc[1]];
    cnt[1] = (tgA + 1 < N) ? (b2 - beg[1]) : 0;
#pragma unroll
    for (int p = 0; p < 2; ++p) {
      int tg = tgA + p;
      unsigned xs = xb32[(size_t)tgc[p] * 64 + l];
      bool keep;
      if (flag == 0)      keep = ((const int*)maskp)[tgc[p]] != 0;
      else if (flag == 1) keep = ((const unsigned char*)maskp)[tgc[p]] != 0;
      else                keep = ((const float*)maskp)[tgc[p]] != 0.f;
      float ms = (keep && tg < N) ? 1.f : 0.f;
      float slo = __uint_as_float(xs << 16);
      float shi = __uint_as_float(xs & 0xFFFF0000u);
#pragma unroll
      for (int b = 0; b < 8; ++b) {
        float a = ms * ctab[256 + b];
        zlo[p][b] = a * slo;
        zhi[p][b] = a * shi;
      }
      srw0[p] = make_uint2(0u, 0u);
      srw1[p] = make_uint2(0u, 0u);
      x0[p] = 0u;
      if (cnt[p] > 0) srw0[p] = msrw[beg[p]];
      if (cnt[p] > 1) srw1[p] = msrw[beg[p] + 1];
      if (cnt[p] > 0) x0[p] = xb32[(size_t)(srw0[p].x & 0xFFFFFFu) * 64 + l];
    }
    int mmax = max(cnt[0], cnt[1]);
    for (int m = 0; m < mmax; ++m) {
#pragma unroll
      for (int p = 0; p < 2; ++p) {
        if (m < cnt[p]) {  // wave-uniform
          int i2 = (m + 2 < cnt[p]) ? (beg[p] + m + 2) : beg[p];
          uint2 srw2 = msrw[i2];
          unsigned x1 = xb32[(size_t)(srw1[p].x & 0xFFFFFFu) * 64 + l];
          int rel = srw0[p].x >> 24;
          float w = __uint_as_float(srw0[p].y);
          f32x4 c0 = *(const f32x4*)&ctab[rel * 8];
          f32x4 c1 = *(const f32x4*)&ctab[rel * 8 + 4];
          float cc[8] = {c0[0], c0[1], c0[2], c0[3], c1[0], c1[1], c1[2], c1[3]};
          float lo = __uint_as_float(x0[p] << 16);
          float hi = __uint_as_float(x0[p] & 0xFFFF0000u);
#pragma unroll
          for (int b = 0; b < 8; ++b) {
            float a = w * cc[b];
            zlo[p][b] = fmaf(a, lo, zlo[p][b]);
            zhi[p][b] = fmaf(a, hi, zhi[p][b]);
          }
          srw0[p] = srw1[p]; x0[p] = x1; srw1[p] = srw2;
        }
      }
    }
    // flush both rows to LDS (bf16, XOR swizzle)
#pragma unroll
    for (int p = 0; p < 2; ++p) {
      int row = wid * 4 + pr * 2 + p;
#pragma unroll
      for (int b = 0; b < 8; ++b) {
        unsigned pk = (unsigned)f2bf(zlo[p][b]) | ((unsigned)f2bf(zhi[p][b]) << 16);
        int byte = row * 2048 + ((b * 256 + l * 4) ^ ((row & 7) << 4));
        *(unsigned*)(smem + byte) = pk;
      }
    }
  }
  __syncthreads();

  // MFMA: out[32 x 128] = Z(32 x 1024) @ Bstack(1024 x 128); wave owns 16 cols, 2 row-tiles
  int l15 = l & 15, lk8 = (l >> 4) * 8;
  f32x4 acc[2] = {};
  for (int ks = 0; ks < 32; ++ks) {
    int k0 = ks * 32 + lk8;
    bf16x8 a[2], bb;
#pragma unroll
    for (int rt = 0; rt < 2; ++rt) {
      int tr = rt * 16 + l15;
      int byte = tr * 2048 + ((k0 * 2) ^ ((tr & 7) << 4));
      a[rt] = *(const bf16x8*)(smem + byte);
    }
    int col = wid * 16 + l15;
    bb = *(const bf16x8*)(bmt + (size_t)col * 1024 + k0);
#pragma unroll
    for (int rt = 0; rt < 2; ++rt)
      acc[rt] = __builtin_amdgcn_mfma_f32_16x16x32_bf16(a[rt], bb, acc[rt], 0, 0, 0);
  }
#pragma unroll
  for (int rt = 0; rt < 2; ++rt) {
    int rowb = t0 + rt * 16 + (l >> 4) * 4;
    int col = wid * 16 + l15;
#pragma unroll
    for (int i = 0; i < 4; ++i) {
      int row = rowb + i;
      if (row < N) out[(size_t)row * 128 + col] = acc[rt][i];
    }
  }
}

extern "C" void kernel_launch(void* const* d_in, const int* in_sizes, int n_in,
                              void* d_out, int out_size, void* d_ws, size_t ws_size,
                              hipStream_t stream) {
  const float* x = (const float*)d_in[0];
  const void* mask = d_in[1];
  const int* source = (const int*)d_in[2];
  const int* target = (const int*)d_in[3];
  const int* etype = (const int*)d_in[4];
  const float* eweight = (const float*)d_in[5];
  const float* bases = (const float*)d_in[6];
  const float* rbw = (const float*)d_in[7];
  float* out = (float*)d_out;

  const int N = in_sizes[1];   // mask element count == num nodes
  const int E = in_sizes[2];
  const int M = 2 * E;
  const int NB = (N + 255) / 256;

  // workspace layout (256B aligned)
  char* ws = (char*)d_ws;
  size_t off = 0;
  unsigned short* xb = (unsigned short*)(ws + off); off += (size_t)N * 256;        // bf16 x
  unsigned short* bmt = (unsigned short*)(ws + off); off += 128 * 1024 * 2;        // BmatT
  uint2* msrw = (uint2*)(ws + off); off += (size_t)(M + 4) * 8;                    // (src|rel, w)
  int* base = (int*)(ws + off); off += ((size_t)N + 64) * 4;                       // N+1 scan
  int* cursor = (int*)(ws + off); off += ((size_t)N + 64) * 4;
  int* cnt = (int*)(ws + off); off += ((size_t)N + 64) * 4;
  int* bsum = (int*)(ws + off); off += 2048;
  int* bexcl = (int*)(ws + off); off += 2048;
  int* flag = (int*)(ws + off); off += 256;

  hipMemsetAsync(cnt, 0, (size_t)N * 4, stream);
  detect_kernel<<<1, 256, 0, stream>>>((const unsigned char*)mask, N < 8192 ? N : 8192, flag);
  int total8 = (N * 128) / 8;
  conv_kernel<<<(total8 + 255) / 256, 256, 0, stream>>>(x, xb, total8);
  tconv_kernel<<<(128 * 1024 + 255) / 256, 256, 0, stream>>>(bases, bmt);
  hist_kernel<<<(E + 255) / 256, 256, 0, stream>>>(source, target, E, cnt);
  scan1_kernel<<<NB, 256, 0, stream>>>(cnt, N, bsum);
  scan2_kernel<<<1, 512, 0, stream>>>(bsum, NB, bexcl, base, N);
  scan3_kernel<<<NB, 256, 0, stream>>>(cnt, N, bexcl, base, cursor);
  scatter_kernel<<<(E + 255) / 256, 256, 0, stream>>>(source, target, etype, eweight, E,
                                                      cursor, msrw);
  int gblk = (N + 31) / 32;
  size_t shmem = 65536 + 264 * sizeof(float) + 16;
  gather_kernel<<<gblk, 512, shmem, stream>>>((const unsigned*)xb, bmt, base, msrw,
                                              rbw, mask, flag, out, N);
}

// Round 6
// 279.930 us; speedup vs baseline: 1.2180x; 1.0108x over previous
//
#include <hip/hip_runtime.h>

typedef __attribute__((ext_vector_type(8))) __bf16 bf16x8;
typedef __attribute__((ext_vector_type(4))) float f32x4;
typedef __attribute__((ext_vector_type(8))) unsigned short ushortx8;

__device__ inline unsigned short f2bf(float f) {
  unsigned int u = __float_as_uint(f);
  unsigned int r = (u + 0x7FFFu + ((u >> 16) & 1u)) >> 16;  // RNE
  return (unsigned short)r;
}

// ---------------- prep: fused conv | tconv | detect (block-range dispatch) ----------------
__global__ __launch_bounds__(256) void prep_kernel(const float* __restrict__ x,
                                                   unsigned short* __restrict__ xb, int total8,
                                                   const float* __restrict__ bases,
                                                   unsigned short* __restrict__ bmt,
                                                   const unsigned char* __restrict__ mask,
                                                   int mbytes, int* __restrict__ flag_out,
                                                   int CB, int TB) {
  int bid = blockIdx.x;
  if (bid < CB) {
    int id = bid * 256 + threadIdx.x;
    if (id >= total8) return;
    f32x4 f0 = ((const f32x4*)x)[2 * id];
    f32x4 f1 = ((const f32x4*)x)[2 * id + 1];
    ushortx8 r;
    r[0] = f2bf(f0[0]); r[1] = f2bf(f0[1]); r[2] = f2bf(f0[2]); r[3] = f2bf(f0[3]);
    r[4] = f2bf(f1[0]); r[5] = f2bf(f1[1]); r[6] = f2bf(f1[2]); r[7] = f2bf(f1[3]);
    ((ushortx8*)xb)[id] = r;
  } else if (bid < CB + TB) {
    int id = (bid - CB) * 256 + threadIdx.x;
    if (id >= 128 * 1024) return;
    int o = id >> 10, k = id & 1023, b = k >> 7, d = k & 127;
    bmt[id] = f2bf(bases[b * 16384 + d * 128 + o]);
  } else {
    __shared__ int nz_off, big;
    if (threadIdx.x == 0) { nz_off = 0; big = 0; }
    __syncthreads();
    int lnz = 0, lbig = 0;
    for (int i = threadIdx.x; i < mbytes; i += 256) {
      unsigned char v = mask[i];
      if ((i & 3) && v) lnz++;
      if (v > 1) lbig++;
    }
    if (lnz) atomicAdd(&nz_off, lnz);
    if (lbig) atomicAdd(&big, lbig);
    __syncthreads();
    if (threadIdx.x == 0) *flag_out = (nz_off == 0) ? 0 : ((big == 0) ? 1 : 2);
  }
}

// ---------------- S1: histogram over target nodes (both directions) ----------------
__global__ __launch_bounds__(256) void hist_kernel(const int* __restrict__ src,
                                                   const int* __restrict__ tgt, int E,
                                                   int* __restrict__ cnt) {
  int i = blockIdx.x * 256 + threadIdx.x;
  if (i >= E) return;
  atomicAdd(&cnt[tgt[i]], 1);
  atomicAdd(&cnt[src[i]], 1);
}

// ---------------- S2a: per-block sums ----------------
__global__ __launch_bounds__(256) void scan1_kernel(const int* __restrict__ cnt, int N,
                                                    int* __restrict__ bsum) {
  __shared__ int s[256];
  int t = threadIdx.x, i = blockIdx.x * 256 + t;
  s[t] = (i < N) ? cnt[i] : 0;
  __syncthreads();
#pragma unroll
  for (int off = 128; off > 0; off >>= 1) {
    if (t < off) s[t] += s[t + off];
    __syncthreads();
  }
  if (t == 0) bsum[blockIdx.x] = s[0];
}

// ---------------- S2b: scan block sums (nb <= 512) ----------------
__global__ void scan2_kernel(const int* __restrict__ bsum, int nb,
                             int* __restrict__ bexcl, int* __restrict__ base, int N) {
  __shared__ int s[512];
  int t = threadIdx.x;
  int v = (t < nb) ? bsum[t] : 0;
  s[t] = v;
  __syncthreads();
  for (int off = 1; off < 512; off <<= 1) {
    int x = (t >= off) ? s[t - off] : 0;
    __syncthreads();
    s[t] += x;
    __syncthreads();
  }
  if (t < nb) bexcl[t] = s[t] - v;
  if (t == nb - 1) base[N] = s[t];
}

// ---------------- S2c: per-element exclusive base + cursor ----------------
__global__ __launch_bounds__(256) void scan3_kernel(const int* __restrict__ cnt, int N,
                                                    const int* __restrict__ bexcl,
                                                    int* __restrict__ base,
                                                    int* __restrict__ cursor) {
  __shared__ int s[256];
  int t = threadIdx.x, i = blockIdx.x * 256 + t;
  int c = (i < N) ? cnt[i] : 0;
  s[t] = c;
  __syncthreads();
  for (int off = 1; off < 256; off <<= 1) {
    int x = (t >= off) ? s[t - off] : 0;
    __syncthreads();
    s[t] += x;
    __syncthreads();
  }
  if (i < N) {
    int v = bexcl[blockIdx.x] + s[t] - c;
    base[i] = v;
    cursor[i] = v;
  }
}

// ---------------- S3: scatter messages (src|rel, w) into target-sorted array ----------------
__global__ __launch_bounds__(256) void scatter_kernel(const int* __restrict__ src,
                                                      const int* __restrict__ tgt,
                                                      const int* __restrict__ et,
                                                      const float* __restrict__ ew, int E,
                                                      int* __restrict__ cursor,
                                                      uint2* __restrict__ msrw) {
  int i = blockIdx.x * 256 + threadIdx.x;
  if (i >= E) return;
  int s = src[i], g = tgt[i], r = et[i];
  unsigned wbits = __float_as_uint(ew[i]);
  int s1 = atomicAdd(&cursor[g], 1);
  msrw[s1] = make_uint2((unsigned)s | ((unsigned)r << 24), wbits);
  int s2 = atomicAdd(&cursor[s], 1);
  msrw[s2] = make_uint2((unsigned)g | ((unsigned)r << 24), wbits);
}

// ---------------- K: per-target gather + block MFMA projection ----------------
// block = 512 thr (8 waves), owns 32 target rows; wave owns 4 consecutive targets.
// Message phase: lane-parallel msrw block load + shfl broadcast + 8-wide x-row prefetch.
// LDS: zs = 32 rows x 1024 k bf16 (XOR-swizzled), 65536 B; ctab = 264 floats
__global__ __launch_bounds__(512, 4) void gather_kernel(
    const unsigned* __restrict__ xb32, const unsigned short* __restrict__ bmt,
    const int* __restrict__ base, const uint2* __restrict__ msrw,
    const float* __restrict__ rbw, const void* __restrict__ maskp,
    const int* __restrict__ flag_p, float* __restrict__ out, int N) {
  extern __shared__ char smem[];
  float* ctab = (float*)(smem + 65536);  // 264 floats
  int t = threadIdx.x;
  for (int i = t; i < 264; i += 512) ctab[i] = rbw[i];
  int wid = t >> 6, l = t & 63;
  int t0 = blockIdx.x * 32;
  int flag = *flag_p;
  __syncthreads();

  int tgbase = t0 + wid * 4;
  // base[tgbase .. tgbase+4] via 5 lanes + shfl
  int bv = 0;
  if (l < 5) bv = base[min(tgbase + (int)l, N)];
  int baseArr[5];
#pragma unroll
  for (int j = 0; j < 5; ++j) baseArr[j] = __shfl(bv, j);

  // prefetch self rows & masks for the 4 targets
  unsigned xself[4];
  float msk[4];
#pragma unroll
  for (int j = 0; j < 4; ++j) {
    int tg = tgbase + j;
    int tgc = min(tg, N - 1);
    xself[j] = xb32[(size_t)tgc * 64 + l];
    bool keep;
    if (flag == 0)      keep = ((const int*)maskp)[tgc] != 0;
    else if (flag == 1) keep = ((const unsigned char*)maskp)[tgc] != 0;
    else                keep = ((const float*)maskp)[tgc] != 0.f;
    msk[j] = (keep && tg < N) ? 1.f : 0.f;
  }

  // prefetch msrw lane-block for target 0
  uint2 srwl = make_uint2(0u, 0u);
  {
    int c = (tgbase < N) ? (baseArr[1] - baseArr[0]) : 0;
    if (c > 0) srwl = msrw[baseArr[0] + min((int)l, c - 1)];
  }

  for (int j = 0; j < 4; ++j) {
    int tg = tgbase + j;
    int beg = baseArr[j];
    int cnt = (tg < N) ? (baseArr[j + 1] - beg) : 0;
    float zlo[8], zhi[8];
    {
      float slo = __uint_as_float(xself[j] << 16);
      float shi = __uint_as_float(xself[j] & 0xFFFF0000u);
#pragma unroll
      for (int b = 0; b < 8; ++b) {
        float a = msk[j] * ctab[256 + b];
        zlo[b] = a * slo;
        zhi[b] = a * shi;
      }
    }
    uint2 cur = srwl;
    // prefetch next target's msrw block (issued before this target's FMA phase)
    if (j < 3) {
      int cn = (tg + 1 < N) ? (baseArr[j + 2] - baseArr[j + 1]) : 0;
      srwl = make_uint2(0u, 0u);
      if (cn > 0) srwl = msrw[baseArr[j + 1] + min((int)l, cn - 1)];
    }
    for (int mb = 0; mb < cnt; mb += 64) {
      if (mb > 0) cur = msrw[beg + mb + min((int)l, cnt - mb - 1)];
      int blk = min(cnt - mb, 64);
      for (int c0 = 0; c0 < blk; c0 += 8) {
        unsigned sx[8], xr[8];
        float wv[8];
        // pass 1: broadcast message meta + issue 8 independent x-row loads
#pragma unroll
        for (int s = 0; s < 8; ++s) {
          int m = c0 + s;
          int msel = (m < blk) ? m : 0;      // wave-uniform
          unsigned a = __shfl(cur.x, msel);
          unsigned wb = __shfl(cur.y, msel);
          sx[s] = a;
          wv[s] = (m < blk) ? __uint_as_float(wb) : 0.f;
          unsigned row = (m < blk) ? (a & 0xFFFFFFu) : 0u;
          xr[s] = xb32[(size_t)row * 64 + l];
        }
        // pass 2: FMA
#pragma unroll
        for (int s = 0; s < 8; ++s) {
          int rel = (int)(sx[s] >> 24);
          f32x4 cA = *(const f32x4*)&ctab[rel * 8];
          f32x4 cB = *(const f32x4*)&ctab[rel * 8 + 4];
          float cc[8] = {cA[0], cA[1], cA[2], cA[3], cB[0], cB[1], cB[2], cB[3]};
          float lo = __uint_as_float(xr[s] << 16);
          float hi = __uint_as_float(xr[s] & 0xFFFF0000u);
          float w = wv[s];
#pragma unroll
          for (int b = 0; b < 8; ++b) {
            float a = w * cc[b];
            zlo[b] = fmaf(a, lo, zlo[b]);
            zhi[b] = fmaf(a, hi, zhi[b]);
          }
        }
      }
    }
    // flush z row to LDS (bf16, XOR swizzle)
    int row = wid * 4 + j;
#pragma unroll
    for (int b = 0; b < 8; ++b) {
      unsigned pk = (unsigned)f2bf(zlo[b]) | ((unsigned)f2bf(zhi[b]) << 16);
      int byte = row * 2048 + ((b * 256 + l * 4) ^ ((row & 7) << 4));
      *(unsigned*)(smem + byte) = pk;
    }
  }
  __syncthreads();

  // MFMA: out[32 x 128] = Z(32 x 1024) @ Bstack(1024 x 128); wave owns 16 cols, 2 row-tiles
  int l15 = l & 15, lk8 = (l >> 4) * 8;
  f32x4 acc[2] = {};
  for (int ks = 0; ks < 32; ++ks) {
    int k0 = ks * 32 + lk8;
    bf16x8 a[2], bb;
#pragma unroll
    for (int rt = 0; rt < 2; ++rt) {
      int tr = rt * 16 + l15;
      int byte = tr * 2048 + ((k0 * 2) ^ ((tr & 7) << 4));
      a[rt] = *(const bf16x8*)(smem + byte);
    }
    int col = wid * 16 + l15;
    bb = *(const bf16x8*)(bmt + (size_t)col * 1024 + k0);
#pragma unroll
    for (int rt = 0; rt < 2; ++rt)
      acc[rt] = __builtin_amdgcn_mfma_f32_16x16x32_bf16(a[rt], bb, acc[rt], 0, 0, 0);
  }
#pragma unroll
  for (int rt = 0; rt < 2; ++rt) {
    int rowb = t0 + rt * 16 + (l >> 4) * 4;
    int col = wid * 16 + l15;
#pragma unroll
    for (int i = 0; i < 4; ++i) {
      int row = rowb + i;
      if (row < N) out[(size_t)row * 128 + col] = acc[rt][i];
    }
  }
}

extern "C" void kernel_launch(void* const* d_in, const int* in_sizes, int n_in,
                              void* d_out, int out_size, void* d_ws, size_t ws_size,
                              hipStream_t stream) {
  const float* x = (const float*)d_in[0];
  const void* mask = d_in[1];
  const int* source = (const int*)d_in[2];
  const int* target = (const int*)d_in[3];
  const int* etype = (const int*)d_in[4];
  const float* eweight = (const float*)d_in[5];
  const float* bases = (const float*)d_in[6];
  const float* rbw = (const float*)d_in[7];
  float* out = (float*)d_out;

  const int N = in_sizes[1];   // mask element count == num nodes
  const int E = in_sizes[2];
  const int M = 2 * E;
  const int NB = (N + 255) / 256;

  // workspace layout (256B aligned)
  char* ws = (char*)d_ws;
  size_t off = 0;
  unsigned short* xb = (unsigned short*)(ws + off); off += (size_t)N * 256;        // bf16 x
  unsigned short* bmt = (unsigned short*)(ws + off); off += 128 * 1024 * 2;        // BmatT
  uint2* msrw = (uint2*)(ws + off); off += (size_t)(M + 4) * 8;                    // (src|rel, w)
  int* base = (int*)(ws + off); off += ((size_t)N + 64) * 4;                       // N+1 scan
  int* cursor = (int*)(ws + off); off += ((size_t)N + 64) * 4;
  int* cnt = (int*)(ws + off); off += ((size_t)N + 64) * 4;
  int* bsum = (int*)(ws + off); off += 2048;
  int* bexcl = (int*)(ws + off); off += 2048;
  int* flag = (int*)(ws + off); off += 256;

  hipMemsetAsync(cnt, 0, (size_t)N * 4, stream);
  int total8 = (N * 128) / 8;
  int CB = (total8 + 255) / 256;
  int TB = (128 * 1024 + 255) / 256;
  prep_kernel<<<CB + TB + 1, 256, 0, stream>>>(x, xb, total8, bases, bmt,
                                               (const unsigned char*)mask,
                                               N < 8192 ? N : 8192, flag, CB, TB);
  hist_kernel<<<(E + 255) / 256, 256, 0, stream>>>(source, target, E, cnt);
  scan1_kernel<<<NB, 256, 0, stream>>>(cnt, N, bsum);
  scan2_kernel<<<1, 512, 0, stream>>>(bsum, NB, bexcl, base, N);
  scan3_kernel<<<NB, 256, 0, stream>>>(cnt, N, bexcl, base, cursor);
  scatter_kernel<<<(E + 255) / 256, 256, 0, stream>>>(source, target, etype, eweight, E,
                                                      cursor, msrw);
  int gblk = (N + 31) / 32;
  size_t shmem = 65536 + 264 * sizeof(float) + 16;
  gather_kernel<<<gblk, 512, shmem, stream>>>((const unsigned*)xb, bmt, base, msrw,
                                              rbw, mask, flag, out, N);
}